// Round 7
// baseline (192.557 us; speedup 1.0000x reference)
//
#include <hip/hip_runtime.h>
#include <hip/hip_fp16.h>

// Problem: inputs (8, 64, 16, 32, 32) fp32, embedding (1024, 64) fp32
#define THW    16384
#define NTOT   131072
#define KDIM   1024
#define CDIM   64
#define QELEMS 8388608          // 8*64*16*32*32
#define LOSS_OFF 8388608
#define IDX_OFF  8388610
#define BN     64               // queries per block

typedef _Float16 half8   __attribute__((ext_vector_type(8)));
typedef _Float16 half4_t __attribute__((ext_vector_type(4)));
typedef float    f32x4   __attribute__((ext_vector_type(4)));

// ---- prep: zero losses; split E into fp16 hi/lo (lo scaled 2^12) in
// fragment-major order: flat ((tile*2 + kHalf)*64 + lane)*8 + j, where
// lane = lq*16 + ln, code row = tile*16 + ln, c = kHalf*32 + lq*8 + j.
__global__ __launch_bounds__(256) void vq_prep(const float* __restrict__ emb,
        _Float16* __restrict__ EhF, _Float16* __restrict__ ElF,
        float* __restrict__ e2, float* __restrict__ out) {
    const int t = threadIdx.x;
    if (blockIdx.x == 0 && t == 0) { out[LOSS_OFF] = 0.f; out[LOSS_OFF + 1] = 0.f; }
    const int ln   = t >> 4;
    const int g    = t & 15;
    const int tile = blockIdx.x;
    const int row  = tile * 16 + ln;
    const int c0   = g * 4;
    float4 v = *(const float4*)(emb + (size_t)row * CDIM + c0);
    const float xs[4] = {v.x, v.y, v.z, v.w};
    half4_t h, l;
    float s = 0.f;
    #pragma unroll
    for (int j = 0; j < 4; ++j) {
        const _Float16 hj = (_Float16)xs[j];
        const _Float16 lj = (_Float16)((xs[j] - (float)hj) * 4096.0f);
        h[j] = hj; l[j] = lj;
        s = fmaf(xs[j], xs[j], s);
    }
    const int ch = c0 >> 5;
    const int lq = (c0 & 31) >> 3;
    const int j0 = c0 & 7;
    const size_t dst = (((size_t)tile * 2 + ch) * 64 + (lq * 16 + ln)) * 8 + j0;
    *(half4_t*)(EhF + dst) = h;
    *(half4_t*)(ElF + dst) = l;
    #pragma unroll
    for (int off = 1; off < 16; off <<= 1) s += __shfl_xor(s, off, 64);
    if (g == 0) e2[row] = s;
}

// ---- main: depth-2 prefetch (4 rotating buffers) fp16x2 MFMA k-loop ----
__global__ __launch_bounds__(256, 3) void vq_main(const float* __restrict__ in,
        const float* __restrict__ emb,
        const _Float16* __restrict__ EhF, const _Float16* __restrict__ ElF,
        const float* __restrict__ e2, float* __restrict__ out) {

    __shared__ char smem[18688];
    float (*Xs)[68] = (float (*)[68])smem;                 // [64][68] = 17408 B
    float (*Q)[68]  = (float (*)[68])smem;                 // epilogue alias
    float* mv   = (float*)smem;                            // [2][64] alias
    int*   mi   = (int*)(smem + 512);                      // [2][64] alias
    float* x2p4 = (float*)(smem + 17408);                  // [4][64]
    int*   idxs = (int*)(smem + 18432);                    // [64]

    const int tid  = threadIdx.x;
    const int n0   = blockIdx.x * BN;
    const int bb   = n0 >> 14;
    const int thw0 = n0 & (THW - 1);
    const float* inb = in  + (size_t)bb * CDIM * THW + thw0;
    float*      outb = out + (size_t)bb * CDIM * THW + thw0;

    // ---- stage X tile ([n][c] transpose) + ||x||^2 partials ----
    {
        const int nl = tid & 63;
        const int cq = tid >> 6;               // 0..3
        float s = 0.f;
        #pragma unroll
        for (int r = 0; r < 16; ++r) {
            const int c = r * 4 + cq;
            const float x = inb[(size_t)c * THW + nl];
            Xs[nl][c] = x;
            s = fmaf(x, x, s);
        }
        x2p4[cq * 64 + nl] = s;
    }
    __syncthreads();

    const int lane = tid & 63;
    const int w    = tid >> 6;
    const int ln   = lane & 15;
    const int lq   = lane >> 4;
    const int qh   = w >> 1;        // query half: 32 queries
    const int tp   = w & 1;         // tile parity: 32 of 64 tiles

    // ---- B fragments (fp16 hi/lo), register-resident ----
    half8 Bh[2][2], Bl[2][2];
    #pragma unroll
    for (int qg = 0; qg < 2; ++qg) {
        const int q = qh * 32 + qg * 16 + ln;
        #pragma unroll
        for (int ch = 0; ch < 2; ++ch) {
            const float* xp = &Xs[q][ch * 32 + lq * 8];
            const float4 xa = *(const float4*)(xp);
            const float4 xb = *(const float4*)(xp + 4);
            const float xv[8] = {xa.x, xa.y, xa.z, xa.w, xb.x, xb.y, xb.z, xb.w};
            #pragma unroll
            for (int j = 0; j < 8; ++j) {
                const _Float16 h = (_Float16)xv[j];
                const _Float16 l = (_Float16)((xv[j] - (float)h) * 4096.0f);
                Bh[qg][ch][j] = h;
                Bl[qg][ch][j] = l;
            }
        }
    }
    __syncthreads();   // Xs dead; mv/mi alias written after k-loop

    float bestv[2] = {3.4e38f, 3.4e38f};
    int   besti[2] = {0, 0};

    const half8* ph = (const half8*)EhF + (size_t)tp * 128 + lane;
    const half8* pl = (const half8*)ElF + (size_t)tp * 128 + lane;
    const f32x4* pe4 = (const f32x4*)e2 + tp * 4 + lq;   // + m*8 per iter

    // 4 rotating buffers, prefetch depth 2
    half8 Ah0[4], Ah1[4], Al0[4], Al1[4];
    f32x4 e2r[4];
    Ah0[0] = ph[0];    Ah1[0] = ph[64];
    Al0[0] = pl[0];    Al1[0] = pl[64];
    e2r[0] = pe4[0];
    Ah0[1] = ph[256];  Ah1[1] = ph[320];
    Al0[1] = pl[256];  Al1[1] = pl[320];
    e2r[1] = pe4[8];

    #pragma unroll 4
    for (int m = 0; m < 32; ++m) {
        const int cur = m & 3;
        if (m < 30) {   // prefetch iteration m+2 into buffer (m+2)%4
            const int nxt = (m + 2) & 3;
            const size_t o = (size_t)(m + 2) * 256;
            Ah0[nxt] = ph[o];  Ah1[nxt] = ph[o + 64];
            Al0[nxt] = pl[o];  Al1[nxt] = pl[o + 64];
            e2r[nxt] = pe4[(m + 2) * 8];
        }
        const int t = tp + 2 * m;
        const float e2a[4] = {e2r[cur].x, e2r[cur].y, e2r[cur].z, e2r[cur].w};
        #pragma unroll
        for (int qg = 0; qg < 2; ++qg) {
            f32x4 a0 = {0.f, 0.f, 0.f, 0.f};
            f32x4 a1 = {0.f, 0.f, 0.f, 0.f};
            a0 = __builtin_amdgcn_mfma_f32_16x16x32_f16(Ah0[cur], Bh[qg][0], a0, 0, 0, 0);
            a0 = __builtin_amdgcn_mfma_f32_16x16x32_f16(Ah1[cur], Bh[qg][1], a0, 0, 0, 0);
            a1 = __builtin_amdgcn_mfma_f32_16x16x32_f16(Ah0[cur], Bl[qg][0], a1, 0, 0, 0);
            a1 = __builtin_amdgcn_mfma_f32_16x16x32_f16(Al0[cur], Bh[qg][0], a1, 0, 0, 0);
            a1 = __builtin_amdgcn_mfma_f32_16x16x32_f16(Ah1[cur], Bl[qg][1], a1, 0, 0, 0);
            a1 = __builtin_amdgcn_mfma_f32_16x16x32_f16(Al1[cur], Bh[qg][1], a1, 0, 0, 0);
            #pragma unroll
            for (int r = 0; r < 4; ++r) {
                const float d = fmaf(-2.0f, a0[r], fmaf(-4.8828125e-4f, a1[r], e2a[r]));
                const int kg = t * 16 + lq * 4 + r;
                if (d < bestv[qg]) { bestv[qg] = d; besti[qg] = kg; }
            }
        }
    }

    // ---- wave-internal argmin reduce across the 4 row-quads ----
    #pragma unroll
    for (int qg = 0; qg < 2; ++qg) {
        #pragma unroll
        for (int msk = 16; msk <= 32; msk <<= 1) {
            const float ov = __shfl_xor(bestv[qg], msk, 64);
            const int   oi = __shfl_xor(besti[qg], msk, 64);
            if (ov < bestv[qg] || (ov == bestv[qg] && oi < besti[qg])) {
                bestv[qg] = ov; besti[qg] = oi;
            }
        }
    }
    if (lq == 0) {
        #pragma unroll
        for (int qg = 0; qg < 2; ++qg) {
            const int q = qh * 32 + qg * 16 + ln;
            mv[tp * 64 + q] = bestv[qg];
            mi[tp * 64 + q] = besti[qg];
        }
    }
    __syncthreads();

    // ---- merge tile parities; indices; loss = sum(bestd + ||x||^2) ----
    float lsum = 0.f;
    if (tid < 64) {
        const int q = tid;
        float v0 = mv[q]; int i0 = mi[q];
        const float v1 = mv[64 + q]; const int i1 = mi[64 + q];
        if (v1 < v0 || (v1 == v0 && i1 < i0)) { v0 = v1; i0 = i1; }
        idxs[q] = i0;
        out[IDX_OFF + n0 + q] = (float)i0;
        lsum = v0 + x2p4[q] + x2p4[64 + q] + x2p4[128 + q] + x2p4[192 + q];
    }
    if (w == 0) {
        #pragma unroll
        for (int off = 32; off > 0; off >>= 1) lsum += __shfl_down(lsum, off, 64);
        if (lane == 0) {
            atomicAdd(&out[LOSS_OFF],     lsum * (1.0f  / (float)QELEMS));
            atomicAdd(&out[LOSS_OFF + 1], lsum * (0.25f / (float)QELEMS));
        }
    }
    __syncthreads();

    // ---- epilogue: gather code rows into LDS, transpose-write ----
    {
        const int q    = tid >> 2;
        const int part = tid & 3;
        const float* er = emb + (size_t)idxs[q] * CDIM + part * 16;
        #pragma unroll
        for (int j = 0; j < 4; ++j) {
            const float4 v = *(const float4*)(er + 4 * j);
            *(float4*)(&Q[q][part * 16 + 4 * j]) = v;
        }
    }
    __syncthreads();
    {
        const int nl = tid & 63;
        const int cb = tid >> 6;
        #pragma unroll
        for (int r = 0; r < 16; ++r) {
            const int c = r * 4 + cb;
            outb[(size_t)c * THW + nl] = Q[nl][c];
        }
    }
}

extern "C" void kernel_launch(void* const* d_in, const int* in_sizes, int n_in,
                              void* d_out, int out_size, void* d_ws, size_t ws_size,
                              hipStream_t stream) {
    const float* in  = (const float*)d_in[0];   // (8, 64, 16, 32, 32) fp32
    const float* emb = (const float*)d_in[1];   // (1024, 64) fp32
    float* out = (float*)d_out;
    _Float16* EhF = (_Float16*)d_ws;                        // 64 tiles * 1024 halves
    _Float16* ElF = (_Float16*)((char*)d_ws + 131072);
    float*    e2  = (float*)((char*)d_ws + 262144);         // 1024 floats

    vq_prep<<<KDIM / 16, 256, 0, stream>>>(emb, EhF, ElF, e2, out);
    vq_main<<<NTOT / BN, 256, 0, stream>>>(in, emb, EhF, ElF, e2, out);
}

// Round 8
// 145.527 us; speedup vs baseline: 1.3232x; 1.3232x over previous
//
#include <hip/hip_runtime.h>
#include <hip/hip_fp16.h>

// Problem: inputs (8, 64, 16, 32, 32) fp32, embedding (1024, 64) fp32
#define THW    16384
#define NTOT   131072
#define KDIM   1024
#define CDIM   64
#define QELEMS 8388608          // 8*64*16*32*32
#define LOSS_OFF 8388608
#define IDX_OFF  8388610
#define BN     128              // queries per block (4 waves x 32 queries)

typedef _Float16 half8   __attribute__((ext_vector_type(8)));
typedef _Float16 half4_t __attribute__((ext_vector_type(4)));
typedef float    f32x4   __attribute__((ext_vector_type(4)));

// ---- prep: zero losses; split E into fp16 hi/lo (lo scaled 2^12) in
// fragment-major order: flat ((tile*2 + kHalf)*64 + lane)*8 + j, where
// lane = lq*16 + ln, code row = tile*16 + ln, c = kHalf*32 + lq*8 + j.
__global__ __launch_bounds__(256) void vq_prep(const float* __restrict__ emb,
        _Float16* __restrict__ EhF, _Float16* __restrict__ ElF,
        float* __restrict__ e2, float* __restrict__ out) {
    const int t = threadIdx.x;
    if (blockIdx.x == 0 && t == 0) { out[LOSS_OFF] = 0.f; out[LOSS_OFF + 1] = 0.f; }
    const int ln   = t >> 4;
    const int g    = t & 15;
    const int tile = blockIdx.x;
    const int row  = tile * 16 + ln;
    const int c0   = g * 4;
    float4 v = *(const float4*)(emb + (size_t)row * CDIM + c0);
    const float xs[4] = {v.x, v.y, v.z, v.w};
    half4_t h, l;
    float s = 0.f;
    #pragma unroll
    for (int j = 0; j < 4; ++j) {
        const _Float16 hj = (_Float16)xs[j];
        const _Float16 lj = (_Float16)((xs[j] - (float)hj) * 4096.0f);
        h[j] = hj; l[j] = lj;
        s = fmaf(xs[j], xs[j], s);
    }
    const int ch = c0 >> 5;
    const int lq = (c0 & 31) >> 3;
    const int j0 = c0 & 7;
    const size_t dst = (((size_t)tile * 2 + ch) * 64 + (lq * 16 + ln)) * 8 + j0;
    *(half4_t*)(EhF + dst) = h;
    *(half4_t*)(ElF + dst) = l;
    #pragma unroll
    for (int off = 1; off < 16; off <<= 1) s += __shfl_xor(s, off, 64);
    if (g == 0) e2[row] = s;
}

// ---- main: 4 waves share one tile stream (L1 reuse), q_w=32, depth-1 prefetch ----
__global__ __launch_bounds__(256, 4) void vq_main(const float* __restrict__ in,
        const float* __restrict__ emb,
        const _Float16* __restrict__ EhF, const _Float16* __restrict__ ElF,
        const float* __restrict__ e2, float* __restrict__ out) {

    __shared__ char smem[36416];
    float (*Xs)[68] = (float (*)[68])smem;                 // [128][68] = 34816 B
    float (*Q)[68]  = (float (*)[68])smem;                 // epilogue alias
    float* x2p  = (float*)(smem + 34816);                  // [2][128]
    int*   idxs = (int*)(smem + 35840);                    // [128]
    float* wsum = (float*)(smem + 36352);                  // [4]

    const int tid  = threadIdx.x;
    const int n0   = blockIdx.x * BN;
    const int bb   = n0 >> 14;
    const int thw0 = n0 & (THW - 1);
    const float* inb = in  + (size_t)bb * CDIM * THW + thw0;
    float*      outb = out + (size_t)bb * CDIM * THW + thw0;

    // ---- stage X tile ([n][c] transpose) + ||x||^2 partials ----
    {
        const int nl = tid & 127;
        const int hf = tid >> 7;
        float s = 0.f;
        #pragma unroll 8
        for (int r = 0; r < 32; ++r) {
            const int c = hf * 32 + r;
            const float x = inb[(size_t)c * THW + nl];
            Xs[nl][c] = x;
            s = fmaf(x, x, s);
        }
        x2p[hf * 128 + nl] = s;
    }
    __syncthreads();

    const int lane = tid & 63;
    const int w    = tid >> 6;      // wave owns queries w*32 .. w*32+31
    const int ln   = lane & 15;
    const int lq   = lane >> 4;

    // ---- B fragments (fp16 hi/lo), register-resident ----
    half8 Bh[2][2], Bl[2][2];
    #pragma unroll
    for (int qg = 0; qg < 2; ++qg) {
        const int q = w * 32 + qg * 16 + ln;
        #pragma unroll
        for (int ch = 0; ch < 2; ++ch) {
            const float* xp = &Xs[q][ch * 32 + lq * 8];
            const float4 xa = *(const float4*)(xp);
            const float4 xb = *(const float4*)(xp + 4);
            const float xv[8] = {xa.x, xa.y, xa.z, xa.w, xb.x, xb.y, xb.z, xb.w};
            #pragma unroll
            for (int j = 0; j < 8; ++j) {
                const _Float16 h = (_Float16)xv[j];
                const _Float16 l = (_Float16)((xv[j] - (float)h) * 4096.0f);
                Bh[qg][ch][j] = h;
                Bl[qg][ch][j] = l;
            }
        }
    }

    float bestv[2] = {3.4e38f, 3.4e38f};
    int   besti[2] = {0, 0};

    const half8* ph  = (const half8*)EhF + lane;        // tile m at +m*128
    const half8* pl  = (const half8*)ElF + lane;
    const f32x4* pe4 = (const f32x4*)e2 + lq;           // tile m at +m*4

    // depth-1 prefetch, 2 buffers (round-5 proven)
    half8 Ah0[2], Ah1[2], Al0[2], Al1[2];
    f32x4 e2r[2];
    Ah0[0] = ph[0];  Ah1[0] = ph[64];
    Al0[0] = pl[0];  Al1[0] = pl[64];
    e2r[0] = pe4[0];

    #pragma unroll 2
    for (int m = 0; m < 64; ++m) {
        const int cur = m & 1;
        const int nxt = cur ^ 1;
        if (m < 63) {
            const size_t o = (size_t)(m + 1) * 128;
            Ah0[nxt] = ph[o];  Ah1[nxt] = ph[o + 64];
            Al0[nxt] = pl[o];  Al1[nxt] = pl[o + 64];
            e2r[nxt] = pe4[(m + 1) * 4];
        }
        const float e2a[4] = {e2r[cur].x, e2r[cur].y, e2r[cur].z, e2r[cur].w};
        #pragma unroll
        for (int qg = 0; qg < 2; ++qg) {
            f32x4 a0 = {0.f, 0.f, 0.f, 0.f};
            f32x4 a1 = {0.f, 0.f, 0.f, 0.f};
            a0 = __builtin_amdgcn_mfma_f32_16x16x32_f16(Ah0[cur], Bh[qg][0], a0, 0, 0, 0);
            a0 = __builtin_amdgcn_mfma_f32_16x16x32_f16(Ah1[cur], Bh[qg][1], a0, 0, 0, 0);
            a1 = __builtin_amdgcn_mfma_f32_16x16x32_f16(Ah0[cur], Bl[qg][0], a1, 0, 0, 0);
            a1 = __builtin_amdgcn_mfma_f32_16x16x32_f16(Al0[cur], Bh[qg][0], a1, 0, 0, 0);
            a1 = __builtin_amdgcn_mfma_f32_16x16x32_f16(Ah1[cur], Bl[qg][1], a1, 0, 0, 0);
            a1 = __builtin_amdgcn_mfma_f32_16x16x32_f16(Al1[cur], Bh[qg][1], a1, 0, 0, 0);
            #pragma unroll
            for (int r = 0; r < 4; ++r) {
                const float d = fmaf(-2.0f, a0[r], fmaf(-4.8828125e-4f, a1[r], e2a[r]));
                const int kg = m * 16 + lq * 4 + r;
                if (d < bestv[qg]) { bestv[qg] = d; besti[qg] = kg; }
            }
        }
    }

    // ---- wave-internal argmin reduce across the 4 row-quads (final per query) ----
    #pragma unroll
    for (int qg = 0; qg < 2; ++qg) {
        #pragma unroll
        for (int msk = 16; msk <= 32; msk <<= 1) {
            const float ov = __shfl_xor(bestv[qg], msk, 64);
            const int   oi = __shfl_xor(besti[qg], msk, 64);
            if (ov < bestv[qg] || (ov == bestv[qg] && oi < besti[qg])) {
                bestv[qg] = ov; besti[qg] = oi;
            }
        }
    }
    float lsum = 0.f;
    if (lq == 0) {
        #pragma unroll
        for (int qg = 0; qg < 2; ++qg) {
            const int q = w * 32 + qg * 16 + ln;
            idxs[q] = besti[qg];
            out[IDX_OFF + n0 + q] = (float)besti[qg];
            lsum += bestv[qg] + x2p[q] + x2p[128 + q];
        }
    }
    #pragma unroll
    for (int off = 32; off > 0; off >>= 1) lsum += __shfl_down(lsum, off, 64);
    if (lane == 0) wsum[w] = lsum;
    __syncthreads();
    if (tid == 0) {
        const float s = wsum[0] + wsum[1] + wsum[2] + wsum[3];
        atomicAdd(&out[LOSS_OFF],     s * (1.0f  / (float)QELEMS));
        atomicAdd(&out[LOSS_OFF + 1], s * (0.25f / (float)QELEMS));
    }

    // ---- epilogue: gather code rows into LDS (Q aliases dead Xs), transpose-write ----
    {
        const int q  = tid >> 1;
        const int hf = tid & 1;
        const float* er = emb + (size_t)idxs[q] * CDIM + hf * 32;
        #pragma unroll
        for (int j = 0; j < 8; ++j) {
            const float4 v = *(const float4*)(er + 4 * j);
            *(float4*)(&Q[q][hf * 32 + 4 * j]) = v;
        }
    }
    __syncthreads();
    {
        const int nl = tid & 127;
        const int cb = tid >> 7;
        #pragma unroll 8
        for (int r = 0; r < 32; ++r) {
            const int c = 2 * r + cb;
            outb[(size_t)c * THW + nl] = Q[nl][c];
        }
    }
}

extern "C" void kernel_launch(void* const* d_in, const int* in_sizes, int n_in,
                              void* d_out, int out_size, void* d_ws, size_t ws_size,
                              hipStream_t stream) {
    const float* in  = (const float*)d_in[0];   // (8, 64, 16, 32, 32) fp32
    const float* emb = (const float*)d_in[1];   // (1024, 64) fp32
    float* out = (float*)d_out;
    _Float16* EhF = (_Float16*)d_ws;                        // 64 tiles * 1024 halves
    _Float16* ElF = (_Float16*)((char*)d_ws + 131072);
    float*    e2  = (float*)((char*)d_ws + 262144);         // 1024 floats

    vq_prep<<<KDIM / 16, 256, 0, stream>>>(emb, EhF, ElF, e2, out);
    vq_main<<<NTOT / BN, 256, 0, stream>>>(in, emb, EhF, ElF, e2, out);
}

// Round 9
// 145.083 us; speedup vs baseline: 1.3272x; 1.0031x over previous
//
#include <hip/hip_runtime.h>
#include <hip/hip_fp16.h>

// Problem: inputs (8, 64, 16, 32, 32) fp32, embedding (1024, 64) fp32
#define THW    16384
#define NTOT   131072
#define KDIM   1024
#define CDIM   64
#define QELEMS 8388608          // 8*64*16*32*32
#define LOSS_OFF 8388608
#define IDX_OFF  8388610
#define BN     128              // queries per block (4 waves x 32 queries)

typedef _Float16 half8   __attribute__((ext_vector_type(8)));
typedef _Float16 half4_t __attribute__((ext_vector_type(4)));
typedef float    f32x4   __attribute__((ext_vector_type(4)));

// ---- prep: zero losses; split E into fp16 hi/lo (lo scaled 2^12) in
// fragment-major order: flat ((tile*2 + kHalf)*64 + lane)*8 + j, where
// lane = lq*16 + ln, code row = tile*16 + ln, c = kHalf*32 + lq*8 + j.
// Stores me2h[row] = -0.5*||e||^2 (seed for the hh MFMA chain).
__global__ __launch_bounds__(256) void vq_prep(const float* __restrict__ emb,
        _Float16* __restrict__ EhF, _Float16* __restrict__ ElF,
        float* __restrict__ me2h, float* __restrict__ out) {
    const int t = threadIdx.x;
    if (blockIdx.x == 0 && t == 0) { out[LOSS_OFF] = 0.f; out[LOSS_OFF + 1] = 0.f; }
    const int ln   = t >> 4;
    const int g    = t & 15;
    const int tile = blockIdx.x;
    const int row  = tile * 16 + ln;
    const int c0   = g * 4;
    float4 v = *(const float4*)(emb + (size_t)row * CDIM + c0);
    const float xs[4] = {v.x, v.y, v.z, v.w};
    half4_t h, l;
    float s = 0.f;
    #pragma unroll
    for (int j = 0; j < 4; ++j) {
        const _Float16 hj = (_Float16)xs[j];
        const _Float16 lj = (_Float16)((xs[j] - (float)hj) * 4096.0f);
        h[j] = hj; l[j] = lj;
        s = fmaf(xs[j], xs[j], s);
    }
    const int ch = c0 >> 5;
    const int lq = (c0 & 31) >> 3;
    const int j0 = c0 & 7;
    const size_t dst = (((size_t)tile * 2 + ch) * 64 + (lq * 16 + ln)) * 8 + j0;
    *(half4_t*)(EhF + dst) = h;
    *(half4_t*)(ElF + dst) = l;
    #pragma unroll
    for (int off = 1; off < 16; off <<= 1) s += __shfl_xor(s, off, 64);
    if (g == 0) me2h[row] = -0.5f * s;
}

// ---- main: 4 waves share one tile stream; single-acc MFMA chain; s-max fold ----
__global__ __launch_bounds__(256, 3) void vq_main(const float* __restrict__ in,
        const float* __restrict__ emb,
        const _Float16* __restrict__ EhF, const _Float16* __restrict__ ElF,
        const float* __restrict__ me2h, float* __restrict__ out) {

    __shared__ char smem[36416];
    float (*Xs)[68] = (float (*)[68])smem;                 // [128][68] = 34816 B
    float (*Q)[68]  = (float (*)[68])smem;                 // epilogue alias
    float* x2p  = (float*)(smem + 34816);                  // [2][128]
    int*   idxs = (int*)(smem + 35840);                    // [128]
    float* wsum = (float*)(smem + 36352);                  // [4]

    const int tid  = threadIdx.x;
    const int n0   = blockIdx.x * BN;
    const int bb   = n0 >> 14;
    const int thw0 = n0 & (THW - 1);
    const float* inb = in  + (size_t)bb * CDIM * THW + thw0;
    float*      outb = out + (size_t)bb * CDIM * THW + thw0;

    // ---- stage X tile ([n][c] transpose) + ||x||^2 partials ----
    {
        const int nl = tid & 127;
        const int hf = tid >> 7;
        float s = 0.f;
        #pragma unroll 8
        for (int r = 0; r < 32; ++r) {
            const int c = hf * 32 + r;
            const float x = inb[(size_t)c * THW + nl];
            Xs[nl][c] = x;
            s = fmaf(x, x, s);
        }
        x2p[hf * 128 + nl] = s;
    }
    __syncthreads();

    const int lane = tid & 63;
    const int w    = tid >> 6;      // wave owns queries w*32 .. w*32+31
    const int ln   = lane & 15;
    const int lq   = lane >> 4;

    // ---- B fragments (fp16 hi/lo), register-resident ----
    half8 Bh[2][2], Bl[2][2];
    #pragma unroll
    for (int qg = 0; qg < 2; ++qg) {
        const int q = w * 32 + qg * 16 + ln;
        #pragma unroll
        for (int ch = 0; ch < 2; ++ch) {
            const float* xp = &Xs[q][ch * 32 + lq * 8];
            const float4 xa = *(const float4*)(xp);
            const float4 xb = *(const float4*)(xp + 4);
            const float xv[8] = {xa.x, xa.y, xa.z, xa.w, xb.x, xb.y, xb.z, xb.w};
            #pragma unroll
            for (int j = 0; j < 8; ++j) {
                const _Float16 h = (_Float16)xv[j];
                const _Float16 l = (_Float16)((xv[j] - (float)h) * 4096.0f);
                Bh[qg][ch][j] = h;
                Bl[qg][ch][j] = l;
            }
        }
    }

    // maximize s = x.e - 0.5*||e||^2  (argmax s == argmin d, d = -2s)
    float bests[2] = {-3.4e38f, -3.4e38f};
    int   besti[2] = {0, 0};

    const half8* ph  = (const half8*)EhF + lane;        // tile m at +m*128
    const half8* pl  = (const half8*)ElF + lane;
    const f32x4* pe4 = (const f32x4*)me2h + lq;         // tile m at +m*4

    // depth-1 prefetch, 2 buffers
    half8 Ah0[2], Ah1[2], Al0[2], Al1[2];
    f32x4 e2r[2];
    Ah0[0] = ph[0];  Ah1[0] = ph[64];
    Al0[0] = pl[0];  Al1[0] = pl[64];
    e2r[0] = pe4[0];

    #pragma unroll 2
    for (int m = 0; m < 64; ++m) {
        const int cur = m & 1;
        const int nxt = cur ^ 1;
        if (m < 63) {
            const size_t o = (size_t)(m + 1) * 128;
            Ah0[nxt] = ph[o];  Ah1[nxt] = ph[o + 64];
            Al0[nxt] = pl[o];  Al1[nxt] = pl[o + 64];
            e2r[nxt] = pe4[(m + 1) * 4];
        }
        #pragma unroll
        for (int qg = 0; qg < 2; ++qg) {
            // cross terms first (scaled 2^12)
            f32x4 a1 = {0.f, 0.f, 0.f, 0.f};
            a1 = __builtin_amdgcn_mfma_f32_16x16x32_f16(Ah0[cur], Bl[qg][0], a1, 0, 0, 0);
            a1 = __builtin_amdgcn_mfma_f32_16x16x32_f16(Al0[cur], Bh[qg][0], a1, 0, 0, 0);
            a1 = __builtin_amdgcn_mfma_f32_16x16x32_f16(Ah1[cur], Bl[qg][1], a1, 0, 0, 0);
            a1 = __builtin_amdgcn_mfma_f32_16x16x32_f16(Al1[cur], Bh[qg][1], a1, 0, 0, 0);
            // seed hh-chain with 2^-12*a1 - 0.5*||e||^2
            f32x4 c0;
            #pragma unroll
            for (int r = 0; r < 4; ++r)
                c0[r] = fmaf(2.44140625e-4f, a1[r], e2r[cur][r]);
            c0 = __builtin_amdgcn_mfma_f32_16x16x32_f16(Ah0[cur], Bh[qg][0], c0, 0, 0, 0);
            c0 = __builtin_amdgcn_mfma_f32_16x16x32_f16(Ah1[cur], Bh[qg][1], c0, 0, 0, 0);
            // fold: bare compare (ascending k, strict > keeps lowest k)
            #pragma unroll
            for (int r = 0; r < 4; ++r) {
                const int kg = m * 16 + lq * 4 + r;
                if (c0[r] > bests[qg]) { bests[qg] = c0[r]; besti[qg] = kg; }
            }
        }
    }

    // ---- wave-internal argmax reduce across the 4 row-quads ----
    #pragma unroll
    for (int qg = 0; qg < 2; ++qg) {
        #pragma unroll
        for (int msk = 16; msk <= 32; msk <<= 1) {
            const float ov = __shfl_xor(bests[qg], msk, 64);
            const int   oi = __shfl_xor(besti[qg], msk, 64);
            if (ov > bests[qg] || (ov == bests[qg] && oi < besti[qg])) {
                bests[qg] = ov; besti[qg] = oi;
            }
        }
    }
    float lsum = 0.f;
    if (lq == 0) {
        #pragma unroll
        for (int qg = 0; qg < 2; ++qg) {
            const int q = w * 32 + qg * 16 + ln;
            idxs[q] = besti[qg];
            out[IDX_OFF + n0 + q] = (float)besti[qg];
            // d = -2*s ; loss term = d + ||x||^2
            lsum += fmaf(-2.0f, bests[qg], x2p[q] + x2p[128 + q]);
        }
    }
    #pragma unroll
    for (int off = 32; off > 0; off >>= 1) lsum += __shfl_down(lsum, off, 64);
    if (lane == 0) wsum[w] = lsum;
    __syncthreads();
    if (tid == 0) {
        const float s = wsum[0] + wsum[1] + wsum[2] + wsum[3];
        atomicAdd(&out[LOSS_OFF],     s * (1.0f  / (float)QELEMS));
        atomicAdd(&out[LOSS_OFF + 1], s * (0.25f / (float)QELEMS));
    }

    // ---- epilogue: gather code rows into LDS (Q aliases dead Xs), transpose-write ----
    {
        const int q  = tid >> 1;
        const int hf = tid & 1;
        const float* er = emb + (size_t)idxs[q] * CDIM + hf * 32;
        #pragma unroll
        for (int j = 0; j < 8; ++j) {
            const float4 v = *(const float4*)(er + 4 * j);
            *(float4*)(&Q[q][hf * 32 + 4 * j]) = v;
        }
    }
    __syncthreads();
    {
        const int nl = tid & 127;
        const int cb = tid >> 7;
        #pragma unroll 8
        for (int r = 0; r < 32; ++r) {
            const int c = 2 * r + cb;
            outb[(size_t)c * THW + nl] = Q[nl][c];
        }
    }
}

extern "C" void kernel_launch(void* const* d_in, const int* in_sizes, int n_in,
                              void* d_out, int out_size, void* d_ws, size_t ws_size,
                              hipStream_t stream) {
    const float* in  = (const float*)d_in[0];   // (8, 64, 16, 32, 32) fp32
    const float* emb = (const float*)d_in[1];   // (1024, 64) fp32
    float* out = (float*)d_out;
    _Float16* EhF  = (_Float16*)d_ws;                       // 64 tiles * 1024 halves
    _Float16* ElF  = (_Float16*)((char*)d_ws + 131072);
    float*    me2h = (float*)((char*)d_ws + 262144);        // 1024 floats = -0.5*||e||^2

    vq_prep<<<KDIM / 16, 256, 0, stream>>>(emb, EhF, ElF, me2h, out);
    vq_main<<<NTOT / BN, 256, 0, stream>>>(in, emb, EhF, ElF, me2h, out);
}